// Round 1
// baseline (183.553 us; speedup 1.0000x reference)
//
#include <hip/hip_runtime.h>
#include <math.h>

// SoftCodebook fused kernel for MI355X (gfx950).
// p = softmax( (h/||h||) @ (proto/||proto||)^T / 0.1 ),  z = p @ proto
// Strategy: f16 MFMA (16x16x32) for both GEMMs, fp32 softmax, everything fused.
// Prototypes pre-packed into MFMA B-fragment order in d_ws by two tiny prep kernels.

#define EPS 1e-12f
#define TAU_INV 10.0f

typedef _Float16 f16x8 __attribute__((ext_vector_type(8)));
typedef float f32x4 __attribute__((ext_vector_type(4)));

// ---------------------------------------------------------------------------
// Prep 1: per-prototype norm + f16 normalized prototypes.
// grid: 128 blocks (one per prototype row) x 64 threads.
__global__ void k_prep_cbar(const float* __restrict__ proto,
                            float* __restrict__ scale,
                            _Float16* __restrict__ cbar) {
    const int r = blockIdx.x;      // prototype index 0..127
    const int lane = threadIdx.x;  // 0..63, each lane owns 4 of 256 dims
    const float4 v = ((const float4*)(proto + r * 256))[lane];
    float s = v.x * v.x + v.y * v.y + v.z * v.z + v.w * v.w;
    #pragma unroll
    for (int msk = 1; msk < 64; msk <<= 1) s += __shfl_xor(s, msk, 64);
    const float sc = fmaxf(sqrtf(s), EPS);   // max(||c||, eps) — proto = cbar * sc exactly
    const float inv = 1.0f / sc;
    if (lane == 0) scale[r] = sc;
    _Float16* crow = cbar + r * 256 + lane * 4;
    crow[0] = (_Float16)(v.x * inv);
    crow[1] = (_Float16)(v.y * inv);
    crow[2] = (_Float16)(v.z * inv);
    crow[3] = (_Float16)(v.w * inv);
}

// ---------------------------------------------------------------------------
// Prep 2: pack cbar into MFMA B-fragment order for both GEMMs.
// 16x16x32 f16 B layout: lane holds B[k = (lane>>4)*8 + j][n = lane&15], j=0..7.
// sim GEMM:  B[d][kproto] = cbar[kproto][d]   (reduction over d, 8x8 = 64 frags)
// z   GEMM:  B[kk][d]     = cbar[kk][d]       (reduction over kk, 16x4 = 64 frags)
// grid: 128 blocks x 64 threads; block f<64 -> sim frag f, else z frag f-64.
__global__ void k_prep_frag(const _Float16* __restrict__ cbar,
                            f16x8* __restrict__ simfrag,
                            f16x8* __restrict__ zfrag) {
    const int f = blockIdx.x;
    const int lane = threadIdx.x;
    const int m = lane & 15, quad = lane >> 4;
    if (f < 64) {
        const int ktile = f >> 3, chunk = f & 7;
        // element j: d = chunk*32 + quad*8 + j, kproto = ktile*16 + m
        const _Float16* src = cbar + (ktile * 16 + m) * 256 + chunk * 32 + quad * 8;
        simfrag[f * 64 + lane] = *(const f16x8*)src;  // 8 consecutive halves = 16B copy
    } else {
        const int g = f - 64;
        const int dtile = g >> 2, chunk2 = g & 3;
        const int n = dtile * 16 + m;
        const int kk0 = chunk2 * 32 + quad * 8;
        f16x8 v;
        #pragma unroll
        for (int j = 0; j < 8; j++) v[j] = cbar[(kk0 + j) * 256 + n];  // strided gather
        zfrag[g * 64 + lane] = v;
    }
}

// ---------------------------------------------------------------------------
// Main fused kernel. Block = 256 threads = 4 waves; 64 rows per block, 16/wave.
// Per wave: load+normalize 16 h rows into A frags (f16), 64 MFMAs -> sim 16x128
// in fp32 regs, softmax in-register (16-lane shuffles), write p, round-trip
// p*scale through LDS into A-layout, 64 MFMAs -> z 16x256, write z.
__global__ __launch_bounds__(256) void k_main(
    const float* __restrict__ h,
    const float* __restrict__ scale,
    const f16x8* __restrict__ simfrag,
    const f16x8* __restrict__ zfrag,
    float* __restrict__ out_p,
    float* __restrict__ out_z) {

    // +8 f16 pad per row: stride 272B -> 2-way LDS bank aliasing (free on CDNA4)
    __shared__ _Float16 p_lds[4][16][136];

    const int tid = threadIdx.x;
    const int w = tid >> 6;         // wave 0..3
    const int lane = tid & 63;
    const int m = lane & 15;
    const int quad = lane >> 4;
    const int row0 = blockIdx.x * 64 + w * 16;

    // --- load h rows (A layout: lane holds row m, d = chunk*32 + quad*8 + j)
    const float* hrow = h + (size_t)(row0 + m) * 256 + quad * 8;
    float hv[64];
    #pragma unroll
    for (int c = 0; c < 8; c++) {
        const float4 a = *(const float4*)(hrow + c * 32);
        const float4 b = *(const float4*)(hrow + c * 32 + 4);
        hv[c*8+0]=a.x; hv[c*8+1]=a.y; hv[c*8+2]=a.z; hv[c*8+3]=a.w;
        hv[c*8+4]=b.x; hv[c*8+5]=b.y; hv[c*8+6]=b.z; hv[c*8+7]=b.w;
    }
    // --- row norm: lanes {m, m+16, m+32, m+48} hold quarters of row m
    float s = 0.f;
    #pragma unroll
    for (int i = 0; i < 64; i++) s += hv[i] * hv[i];
    s += __shfl_xor(s, 16, 64);
    s += __shfl_xor(s, 32, 64);
    const float inv = 1.0f / fmaxf(sqrtf(s), EPS);

    f16x8 A[8];
    #pragma unroll
    for (int c = 0; c < 8; c++) {
        #pragma unroll
        for (int j = 0; j < 8; j++) A[c][j] = (_Float16)(hv[c*8+j] * inv);
    }

    // --- sim GEMM: acc[t] = 16x16 tile, k = t*16 + (lane&15), row = quad*4 + r
    f32x4 acc[8] = {};
    #pragma unroll
    for (int t = 0; t < 8; t++) {
        #pragma unroll
        for (int c = 0; c < 8; c++) {
            acc[t] = __builtin_amdgcn_mfma_f32_16x16x32_f16(
                A[c], simfrag[(t * 8 + c) * 64 + lane], acc[t], 0, 0, 0);
        }
    }

    // per-lane prototype scales for z (proto = cbar * scale)
    float sc_l[8];
    #pragma unroll
    for (int t = 0; t < 8; t++) sc_l[t] = scale[t * 16 + m];

    // --- softmax over K=128 per row (fp32, within 16-lane quad groups)
    #pragma unroll
    for (int r = 0; r < 4; r++) {
        float mx = acc[0][r];
        #pragma unroll
        for (int t = 1; t < 8; t++) mx = fmaxf(mx, acc[t][r]);
        #pragma unroll
        for (int msk = 1; msk < 16; msk <<= 1) mx = fmaxf(mx, __shfl_xor(mx, msk, 64));
        float e[8];
        float sum = 0.f;
        #pragma unroll
        for (int t = 0; t < 8; t++) {
            e[t] = __expf((acc[t][r] - mx) * TAU_INV);
            sum += e[t];
        }
        #pragma unroll
        for (int msk = 1; msk < 16; msk <<= 1) sum += __shfl_xor(sum, msk, 64);
        const float rs = 1.0f / sum;
        const int grow = row0 + quad * 4 + r;
        float* po = out_p + (size_t)grow * 128;
        #pragma unroll
        for (int t = 0; t < 8; t++) {
            const float p = e[t] * rs;
            po[t * 16 + m] = p;                                  // fp32 p out
            p_lds[w][quad * 4 + r][t * 16 + m] = (_Float16)(p * sc_l[t]);
        }
    }
    __syncthreads();

    // --- z GEMM: A = p*scale from LDS (A layout: row m, kk = c2*32 + quad*8 + j)
    f16x8 Ap[4];
    #pragma unroll
    for (int c2 = 0; c2 < 4; c2++)
        Ap[c2] = *(const f16x8*)&p_lds[w][m][c2 * 32 + quad * 8];

    #pragma unroll
    for (int dt = 0; dt < 16; dt++) {
        f32x4 az = {};
        #pragma unroll
        for (int c2 = 0; c2 < 4; c2++)
            az = __builtin_amdgcn_mfma_f32_16x16x32_f16(
                Ap[c2], zfrag[(dt * 4 + c2) * 64 + lane], az, 0, 0, 0);
        #pragma unroll
        for (int r = 0; r < 4; r++)
            out_z[(size_t)(row0 + quad * 4 + r) * 256 + dt * 16 + m] = az[r];
    }
}

// ---------------------------------------------------------------------------
extern "C" void kernel_launch(void* const* d_in, const int* in_sizes, int n_in,
                              void* d_out, int out_size, void* d_ws, size_t ws_size,
                              hipStream_t stream) {
    const float* h_in  = (const float*)d_in[0];   // (B,P,D) fp32, B*P=65536, D=256
    const float* proto = (const float*)d_in[1];   // (K,D) fp32, K=128

    const int M = in_sizes[0] / 256;              // 65536 rows

    // workspace layout (all 16B-aligned): scale[128]f32 | cbar f16[128][256] |
    // simfrag f16x8[64*64] | zfrag f16x8[64*64]   (~198 KB total)
    float*    scale   = (float*)d_ws;
    _Float16* cbar    = (_Float16*)((char*)d_ws + 1024);
    f16x8*    simfrag = (f16x8*)((char*)d_ws + 1024 + 65536);
    f16x8*    zfrag   = (f16x8*)((char*)d_ws + 1024 + 65536 + 65536);

    float* out_p = (float*)d_out;                 // (M,128)
    float* out_z = out_p + (size_t)M * 128;       // (M,256)

    k_prep_cbar<<<dim3(128), dim3(64), 0, stream>>>(proto, scale, cbar);
    k_prep_frag<<<dim3(128), dim3(64), 0, stream>>>(cbar, simfrag, zfrag);
    k_main<<<dim3(M / 64), dim3(256), 0, stream>>>(h_in, scale, simfrag, zfrag,
                                                   out_p, out_z);
}

// Round 2
// 164.997 us; speedup vs baseline: 1.1125x; 1.1125x over previous
//
#include <hip/hip_runtime.h>
#include <math.h>

// SoftCodebook fused kernel v2 for MI355X (gfx950).
// p = softmax( (h/||h||) @ (proto/||proto||)^T / 0.1 ),  z = p @ proto
// v2: B-fragments staged in LDS via global_load_lds (half-images, 33 KB each),
// 16x16x32 f16 MFMA datapath identical to verified v1. 50 KB LDS -> 3 blocks/CU.

#define EPS 1e-12f
#define TAU_INV 10.0f

typedef _Float16 f16x8 __attribute__((ext_vector_type(8)));
typedef float f32x4 __attribute__((ext_vector_type(4)));
typedef const __attribute__((address_space(1))) void* gptr_t;
typedef __attribute__((address_space(3))) void* lptr_t;

// ws image geometry (all row strides odd in dwords -> <=2-way LDS bank aliasing)
#define CB_STRIDE 130   // halves: 128 d-half + 2 pad; image [128 kp][130]
#define CT_STRIDE 66    // halves: 64 kk-half + 2 pad;  image [256 d][66]
#define IMG_BYTES 33792 // padded image allocation = 33 * 1024 (33 staging chunks)

// ---------------------------------------------------------------------------
// Prep: per-prototype norm + scale, write 4 padded f16 half-images to ws.
//   cb[hd][kp][dl] = cbar[kp][hd*128+dl]   (sim B source, d-contiguous)
//   ct[hk][d][kl]  = cbar[hk*64+kl][d]     (z  B source, kk-contiguous)
// grid: 128 blocks (one per prototype) x 64 threads.
__global__ void k_prep(const float* __restrict__ proto,
                       float* __restrict__ scale,
                       _Float16* __restrict__ cb0, _Float16* __restrict__ cb1,
                       _Float16* __restrict__ ct0, _Float16* __restrict__ ct1) {
    const int kp = blockIdx.x;
    const int lane = threadIdx.x;
    const float4 v = ((const float4*)(proto + kp * 256))[lane];
    float s = v.x * v.x + v.y * v.y + v.z * v.z + v.w * v.w;
    #pragma unroll
    for (int msk = 1; msk < 64; msk <<= 1) s += __shfl_xor(s, msk, 64);
    const float sc = fmaxf(sqrtf(s), EPS);   // proto = cbar * sc exactly
    const float inv = 1.0f / sc;
    if (lane == 0) scale[kp] = sc;
    const int d0 = lane * 4;
    _Float16 c[4];
    c[0] = (_Float16)(v.x * inv); c[1] = (_Float16)(v.y * inv);
    c[2] = (_Float16)(v.z * inv); c[3] = (_Float16)(v.w * inv);
    _Float16* cb = (d0 < 128) ? cb0 : cb1;
    const int dl = d0 & 127;
    #pragma unroll
    for (int i = 0; i < 4; i++) cb[kp * CB_STRIDE + dl + i] = c[i];
    _Float16* ct = (kp < 64) ? ct0 : ct1;
    const int kl = kp & 63;
    #pragma unroll
    for (int i = 0; i < 4; i++) ct[(d0 + i) * CT_STRIDE + kl] = c[i];
}

// ---------------------------------------------------------------------------
__device__ __forceinline__ void stage33(const char* src, char* dst, int w, int lane) {
    // copy 33 KiB in 1-KiB wave-chunks via async global->LDS (width 16)
    #pragma unroll
    for (int it = 0; it < 9; ++it) {
        const int c = it * 4 + w;
        if (c < 33) {
            __builtin_amdgcn_global_load_lds((gptr_t)(src + c * 1024 + lane * 16),
                                             (lptr_t)(dst + c * 1024), 16, 0, 0);
        }
    }
}

__device__ __forceinline__ f16x8 ld8(const _Float16* p) {
    // 8 halves from a dword-aligned (not 16B-aligned) LDS address
    union { uint32_t u[4]; f16x8 v; } r;
    const uint32_t* q = (const uint32_t*)p;
    r.u[0] = q[0]; r.u[1] = q[1]; r.u[2] = q[2]; r.u[3] = q[3];
    return r.v;
}

// ---------------------------------------------------------------------------
// Main: 256 threads = 4 waves, 64 rows/block (16/wave), grid = M/64 = 1024.
// LDS: frag 33792 B (staged 4x: cb0, cb1, ct0, ct1) + pbuf 16640 B = 50432 B.
__global__ __launch_bounds__(256, 2) void k_main(
    const float* __restrict__ h,
    const float* __restrict__ scale,
    const char* __restrict__ cb0, const char* __restrict__ cb1,
    const char* __restrict__ ct0, const char* __restrict__ ct1,
    float* __restrict__ out_p,
    float* __restrict__ out_z) {

    __shared__ _Float16 frag[IMG_BYTES / 2];      // 33792 B
    __shared__ _Float16 pbuf[64 * CB_STRIDE];     // 16640 B, rows=block rows, cols=kk

    const int tid = threadIdx.x;
    const int w = tid >> 6;
    const int lane = tid & 63;
    const int m = lane & 15;
    const int quad = lane >> 4;
    const int row0 = blockIdx.x * 64 + w * 16;

    // --- h loads first (oldest vmcnt), then staging of sim d-half 0
    const float* hrow = h + (size_t)(row0 + m) * 256 + quad * 8;
    float hv[64];
    #pragma unroll
    for (int c = 0; c < 8; c++) {
        const float4 a = *(const float4*)(hrow + c * 32);
        const float4 b = *(const float4*)(hrow + c * 32 + 4);
        hv[c*8+0]=a.x; hv[c*8+1]=a.y; hv[c*8+2]=a.z; hv[c*8+3]=a.w;
        hv[c*8+4]=b.x; hv[c*8+5]=b.y; hv[c*8+6]=b.z; hv[c*8+7]=b.w;
    }
    stage33(cb0, (char*)frag, w, lane);

    // --- row norm (lanes {m,m+16,m+32,m+48} hold quarters of row m)
    float s = 0.f;
    #pragma unroll
    for (int i = 0; i < 64; i++) s += hv[i] * hv[i];
    s += __shfl_xor(s, 16, 64);
    s += __shfl_xor(s, 32, 64);
    const float inv = 1.0f / fmaxf(sqrtf(s), EPS);

    f16x8 A[8];
    #pragma unroll
    for (int c = 0; c < 8; c++) {
        #pragma unroll
        for (int j = 0; j < 8; j++) A[c][j] = (_Float16)(hv[c*8+j] * inv);
    }

    __syncthreads();   // cb0 resident

    // --- sim GEMM phase A: d 0..127 (A chunks 0..3)
    f32x4 acc[8] = {};
    #pragma unroll
    for (int t = 0; t < 8; t++) {
        #pragma unroll
        for (int c = 0; c < 4; c++) {
            const f16x8 B = ld8(&frag[(t * 16 + m) * CB_STRIDE + c * 32 + quad * 8]);
            acc[t] = __builtin_amdgcn_mfma_f32_16x16x32_f16(A[c], B, acc[t], 0, 0, 0);
        }
    }

    __syncthreads();
    stage33(cb1, (char*)frag, w, lane);
    __syncthreads();   // cb1 resident

    // --- sim GEMM phase B: d 128..255 (A chunks 4..7)
    #pragma unroll
    for (int t = 0; t < 8; t++) {
        #pragma unroll
        for (int c = 4; c < 8; c++) {
            const f16x8 B = ld8(&frag[(t * 16 + m) * CB_STRIDE + (c - 4) * 32 + quad * 8]);
            acc[t] = __builtin_amdgcn_mfma_f32_16x16x32_f16(A[c], B, acc[t], 0, 0, 0);
        }
    }

    // per-lane prototype scales for z (proto = cbar * scale)
    float sc_l[8];
    #pragma unroll
    for (int t = 0; t < 8; t++) sc_l[t] = scale[t * 16 + m];

    // --- softmax over K=128 per row (fp32, within 16-lane quad groups)
    #pragma unroll
    for (int r = 0; r < 4; r++) {
        float mx = acc[0][r];
        #pragma unroll
        for (int t = 1; t < 8; t++) mx = fmaxf(mx, acc[t][r]);
        #pragma unroll
        for (int msk = 1; msk < 16; msk <<= 1) mx = fmaxf(mx, __shfl_xor(mx, msk, 64));
        float e[8];
        float sum = 0.f;
        #pragma unroll
        for (int t = 0; t < 8; t++) {
            e[t] = __expf((acc[t][r] - mx) * TAU_INV);
            sum += e[t];
        }
        #pragma unroll
        for (int msk = 1; msk < 16; msk <<= 1) sum += __shfl_xor(sum, msk, 64);
        const float rs = 1.0f / sum;
        const int grow = row0 + quad * 4 + r;
        float* po = out_p + (size_t)grow * 128;
        const int prow = w * 16 + quad * 4 + r;
        #pragma unroll
        for (int t = 0; t < 8; t++) {
            const float p = e[t] * rs;
            po[t * 16 + m] = p;
            pbuf[prow * CB_STRIDE + t * 16 + m] = (_Float16)(p * sc_l[t]);
        }
    }

    __syncthreads();   // all cb1 reads + pbuf writes done
    stage33(ct0, (char*)frag, w, lane);
    __syncthreads();   // ct0 resident

    // --- z GEMM, kk-half 0 (kk 0..63)
    f32x4 zacc[16] = {};
    f16x8 Ap0 = ld8(&pbuf[(w * 16 + m) * CB_STRIDE + 0 * 32 + quad * 8]);
    f16x8 Ap1 = ld8(&pbuf[(w * 16 + m) * CB_STRIDE + 1 * 32 + quad * 8]);
    #pragma unroll
    for (int dt = 0; dt < 16; dt++) {
        const f16x8 B0 = ld8(&frag[(dt * 16 + m) * CT_STRIDE + 0 * 32 + quad * 8]);
        zacc[dt] = __builtin_amdgcn_mfma_f32_16x16x32_f16(Ap0, B0, zacc[dt], 0, 0, 0);
        const f16x8 B1 = ld8(&frag[(dt * 16 + m) * CT_STRIDE + 1 * 32 + quad * 8]);
        zacc[dt] = __builtin_amdgcn_mfma_f32_16x16x32_f16(Ap1, B1, zacc[dt], 0, 0, 0);
    }

    __syncthreads();
    stage33(ct1, (char*)frag, w, lane);
    __syncthreads();   // ct1 resident

    // --- z GEMM, kk-half 1 (kk 64..127)
    Ap0 = ld8(&pbuf[(w * 16 + m) * CB_STRIDE + 64 + quad * 8]);
    Ap1 = ld8(&pbuf[(w * 16 + m) * CB_STRIDE + 96 + quad * 8]);
    #pragma unroll
    for (int dt = 0; dt < 16; dt++) {
        const f16x8 B0 = ld8(&frag[(dt * 16 + m) * CT_STRIDE + 0 * 32 + quad * 8]);
        zacc[dt] = __builtin_amdgcn_mfma_f32_16x16x32_f16(Ap0, B0, zacc[dt], 0, 0, 0);
        const f16x8 B1 = ld8(&frag[(dt * 16 + m) * CT_STRIDE + 1 * 32 + quad * 8]);
        zacc[dt] = __builtin_amdgcn_mfma_f32_16x16x32_f16(Ap1, B1, zacc[dt], 0, 0, 0);
    }

    // --- store z (row base 1 KB aligned; 16 lanes x 4 B = 64 B cache lines)
    #pragma unroll
    for (int dt = 0; dt < 16; dt++) {
        #pragma unroll
        for (int r = 0; r < 4; r++)
            out_z[(size_t)(row0 + quad * 4 + r) * 256 + dt * 16 + m] = zacc[dt][r];
    }
}

// ---------------------------------------------------------------------------
extern "C" void kernel_launch(void* const* d_in, const int* in_sizes, int n_in,
                              void* d_out, int out_size, void* d_ws, size_t ws_size,
                              hipStream_t stream) {
    const float* h_in  = (const float*)d_in[0];   // (B,P,D) fp32, B*P=65536, D=256
    const float* proto = (const float*)d_in[1];   // (K,D) fp32, K=128

    const int M = in_sizes[0] / 256;              // 65536 rows

    // ws: scale[128] f32 (1 KiB slot) | cb0 | cb1 | ct0 | ct1 (33 KiB each)
    float* scale = (float*)d_ws;
    char*  cb0   = (char*)d_ws + 1024;
    char*  cb1   = cb0 + IMG_BYTES;
    char*  ct0   = cb1 + IMG_BYTES;
    char*  ct1   = ct0 + IMG_BYTES;

    float* out_p = (float*)d_out;                 // (M,128)
    float* out_z = out_p + (size_t)M * 128;       // (M,256)

    k_prep<<<dim3(128), dim3(64), 0, stream>>>(proto, scale,
                                               (_Float16*)cb0, (_Float16*)cb1,
                                               (_Float16*)ct0, (_Float16*)ct1);
    k_main<<<dim3(M / 64), dim3(256), 0, stream>>>(h_in, scale, cb0, cb1, ct0, ct1,
                                                   out_p, out_z);
}